// Round 8
// baseline (702.160 us; speedup 1.0000x reference)
//
#include <hip/hip_runtime.h>
#include <math.h>

#define Bb 2
#define Tt 1024
#define Cc 1024
#define Hh 16
#define Dd 64
#define Mm (Bb*Tt)
#define DECAY_SCALE (-0.6065306597126334f)
#define GN_EPS (64e-5f)

typedef __attribute__((ext_vector_type(8))) short short8;   // 8 bf16 (4 VGPRs)
typedef __attribute__((ext_vector_type(4))) float f32x4;    // MFMA acc

struct GemmDesc {
  const float* A;      // used when mixrow < 0 (row stride = K)
  const float* W;      // (N, K) row-major
  float* out;          // (M, N) row-major
  const float* bias;   // per-n bias or nullptr
  int N, K;
  int mixrow;          // >=0: A = token-shift mix of hidden_states with x_mix[mixrow]
  int ep;              // 0 none, 1 tanh, 2 sigmoid(x+bias?), 3 DECAY*sigmoid(x+bias)
};

__device__ __forceinline__ float4 ld4(const float* p){ return *reinterpret_cast<const float4*>(p); }
__device__ __forceinline__ float sigmf(float x){ return 1.f/(1.f+expf(-x)); }

__device__ __forceinline__ float wredsum(float x){
  #pragma unroll
  for (int off=32; off>0; off>>=1) x += __shfl_xor(x, off);
  return x;
}

template<int CTRL>
__device__ __forceinline__ float dppadd(float x){
  return x + __int_as_float(__builtin_amdgcn_update_dpp(0, __float_as_int(x), CTRL, 0xF, 0xF, true));
}

// 16-lane sum (lanes 16k..16k+15), pure DPP (VALU speed, no LDS pipe).
__device__ __forceinline__ float dsum16(float x){
  x = dppadd<0xB1>(x);
  x = dppadd<0x4E>(x);
  x = dppadd<0x141>(x);
  x = dppadd<0x140>(x);
  return x;
}

// two independent 16-lane sums, interleaved (per-step dual-dot within one chain).
__device__ __forceinline__ void dsum16x2(float& x, float& y){
  x = dppadd<0xB1>(x);  y = dppadd<0xB1>(y);
  x = dppadd<0x4E>(x);  y = dppadd<0x4E>(y);
  x = dppadd<0x141>(x); y = dppadd<0x141>(y);
  x = dppadd<0x140>(x); y = dppadd<0x140>(y);
}

// four independent 16-lane sums, interleaved: two chains x (ta, out). Each
// chain's DPP links provide filler instructions for the other chain's
// dependency stalls (single in-order wave).
__device__ __forceinline__ void dsum16x4(float& x, float& y, float& z, float& w){
  x = dppadd<0xB1>(x);  y = dppadd<0xB1>(y);  z = dppadd<0xB1>(z);  w = dppadd<0xB1>(w);
  x = dppadd<0x4E>(x);  y = dppadd<0x4E>(y);  z = dppadd<0x4E>(z);  w = dppadd<0x4E>(w);
  x = dppadd<0x141>(x); y = dppadd<0x141>(y); z = dppadd<0x141>(z); w = dppadd<0x141>(w);
  x = dppadd<0x140>(x); y = dppadd<0x140>(y); z = dppadd<0x140>(z); w = dppadd<0x140>(w);
}

// ---------------- vector-ALU GEMM (LoRA stages only) ----------------
#define BM 64
#define BN 128
#define BK 32

__global__ __launch_bounds__(256) void gemm_kernel(
    GemmDesc d0, GemmDesc d1, GemmDesc d2, GemmDesc d3,
    const float* __restrict__ xmix, const float* __restrict__ hs)
{
  GemmDesc d = (blockIdx.z==0)?d0:(blockIdx.z==1)?d1:(blockIdx.z==2)?d2:d3;
  const int n0 = blockIdx.x * BN;
  if (n0 >= d.N) return;            // block-uniform
  const int m0 = blockIdx.y * BM;
  const int tid = threadIdx.x;
  __shared__ float As[BK][BM+4];
  __shared__ float Bs[BK][BN+4];
  const int ty = tid >> 4, tx = tid & 15;

  float acc[4][8];
  #pragma unroll
  for (int i=0;i<4;++i)
    #pragma unroll
    for (int j=0;j<8;++j) acc[i][j]=0.f;

  const int K = d.K;
  const int nt = K / BK;
  const float* mrow = (d.mixrow >= 0) ? (xmix + (size_t)d.mixrow * Cc) : nullptr;
  float4 pa[2], pb[4];

  auto load_tile = [&](int kt){
    const int kbase = kt * BK;
    #pragma unroll
    for (int u=0;u<2;++u){
      const int li = tid + u*256;
      const int ar = li >> 3;
      const int kk = ((li & 7) << 2) + kbase;
      const int gm = m0 + ar;
      if (mrow){
        float4 h0 = ld4(hs + (size_t)gm*Cc + kk);
        float4 mx = ld4(mrow + kk);
        float4 hp = make_float4(0.f,0.f,0.f,0.f);
        if ((gm & (Tt-1)) != 0) hp = ld4(hs + (size_t)(gm-1)*Cc + kk);
        pa[u].x = h0.x + (hp.x - h0.x)*mx.x;
        pa[u].y = h0.y + (hp.y - h0.y)*mx.y;
        pa[u].z = h0.z + (hp.z - h0.z)*mx.z;
        pa[u].w = h0.w + (hp.w - h0.w)*mx.w;
      } else {
        pa[u] = ld4(d.A + (size_t)gm*K + kk);
      }
    }
    #pragma unroll
    for (int u=0;u<4;++u){
      const int li = tid + u*256;
      const int br = li >> 3;
      const int kk = ((li & 7) << 2) + kbase;
      const int gn = n0 + br;
      pb[u] = (gn < d.N) ? ld4(d.W + (size_t)gn*K + kk) : make_float4(0.f,0.f,0.f,0.f);
    }
  };

  load_tile(0);
  for (int kt=0; kt<nt; ++kt){
    __syncthreads();
    #pragma unroll
    for (int u=0;u<2;++u){
      const int li = tid + u*256;
      const int ar = li >> 3;
      const int kc = (li & 7) << 2;
      As[kc+0][ar] = pa[u].x; As[kc+1][ar] = pa[u].y;
      As[kc+2][ar] = pa[u].z; As[kc+3][ar] = pa[u].w;
    }
    #pragma unroll
    for (int u=0;u<4;++u){
      const int li = tid + u*256;
      const int br = li >> 3;
      const int kc = (li & 7) << 2;
      Bs[kc+0][br] = pb[u].x; Bs[kc+1][br] = pb[u].y;
      Bs[kc+2][br] = pb[u].z; Bs[kc+3][br] = pb[u].w;
    }
    __syncthreads();
    if (kt+1 < nt) load_tile(kt+1);
    #pragma unroll
    for (int kk=0;kk<BK;++kk){
      const float4 a0 = *(const float4*)&As[kk][ty<<2];
      const float4 b0 = *(const float4*)&Bs[kk][tx<<3];
      const float4 b1 = *(const float4*)&Bs[kk][(tx<<3)+4];
      const float av[4] = {a0.x,a0.y,a0.z,a0.w};
      const float bv[8] = {b0.x,b0.y,b0.z,b0.w,b1.x,b1.y,b1.z,b1.w};
      #pragma unroll
      for (int i=0;i<4;++i)
        #pragma unroll
        for (int j=0;j<8;++j)
          acc[i][j] = fmaf(av[i], bv[j], acc[i][j]);
    }
  }

  const int ep = d.ep;
  #pragma unroll
  for (int i=0;i<4;++i){
    const int gm = m0 + (ty<<2) + i;
    float* orow = d.out + (size_t)gm * d.N;
    #pragma unroll
    for (int j=0;j<8;++j){
      const int gn = n0 + (tx<<3) + j;
      if (gn < d.N){
        float x = acc[i][j];
        if (ep==1) x = tanhf(x);
        else if (ep==2){ if (d.bias) x += d.bias[gn]; x = sigmf(x); }
        else if (ep==3){ x += d.bias[gn]; x = DECAY_SCALE * sigmf(x); }
        orow[gn] = x;
      }
    }
  }
}

// ---------------- weight split pre-pass (fp32 -> bf16 hi/lo planes) ----------------
#define NPL (Cc*Cc)
__global__ __launch_bounds__(256) void wsplit_kernel(
    const float* __restrict__ s0, const float* __restrict__ s1,
    const float* __restrict__ s2, const float* __restrict__ s3,
    unsigned short* __restrict__ planes)
{
  const int z = blockIdx.z;
  const float* src = z==0?s0:z==1?s1:z==2?s2:s3;
  unsigned short* dh = planes + (size_t)z*2*NPL;
  unsigned short* dl = dh + NPL;
  const size_t i = ((size_t)blockIdx.x*256 + threadIdx.x)*4;
  float4 v = ld4(src + i);
  const float xs[4] = {v.x, v.y, v.z, v.w};
  unsigned hw[2], lw[2];
  #pragma unroll
  for (int c=0;c<2;++c){
    unsigned u0 = __float_as_uint(xs[2*c]);
    unsigned u1 = __float_as_uint(xs[2*c+1]);
    float l0 = xs[2*c]   - __uint_as_float(u0 & 0xFFFF0000u);
    float l1 = xs[2*c+1] - __uint_as_float(u1 & 0xFFFF0000u);
    hw[c] = (u0>>16) | (u1 & 0xFFFF0000u);
    lw[c] = (__float_as_uint(l0)>>16) | (__float_as_uint(l1) & 0xFFFF0000u);
  }
  uint2 hv; hv.x = hw[0]; hv.y = hw[1];
  uint2 lv; lv.x = lw[0]; lv.y = lw[1];
  *(uint2*)(dh + i) = hv;
  *(uint2*)(dl + i) = lv;
}

// ---------------- split-bf16 MFMA GEMM (big projections) ----------------
#define TM 128
#define TN 128
#define LDBS 40   // bf16 row stride in LDS

__global__ __launch_bounds__(256) void gemm_mfma(
    GemmDesc d0, GemmDesc d1, GemmDesc d2,
    const unsigned short* __restrict__ WH0, const unsigned short* __restrict__ WL0,
    const unsigned short* __restrict__ WH1, const unsigned short* __restrict__ WL1,
    const unsigned short* __restrict__ WH2, const unsigned short* __restrict__ WL2,
    const float* __restrict__ xmix, const float* __restrict__ hs)
{
  const int z = blockIdx.z;
  GemmDesc d = z==0?d0:(z==1?d1:d2);
  const unsigned short* WH = z==0?WH0:(z==1?WH1:WH2);
  const unsigned short* WL = z==0?WL0:(z==1?WL1:WL2);
  const int m0 = blockIdx.y * TM;
  const int n0 = blockIdx.x * TN;
  const int K  = d.K;
  const int tid = threadIdx.x;

  __shared__ __align__(16) unsigned short Ah[TM*LDBS], Al[TM*LDBS];
  __shared__ __align__(16) unsigned short Bh[TN*LDBS], Bl[TN*LDBS];

  const int sr = tid >> 1;
  const int sk = (tid & 1) << 4;
  const int gmA = m0 + sr;
  const int gnB = n0 + sr;
  const float* mrow = (d.mixrow >= 0) ? (xmix + (size_t)d.mixrow * Cc) : nullptr;

  float4 pa[4];
  uint4 pwh[2], pwl[2];
  auto load_slab = [&](int kt){
    const int kb = kt*32 + sk;
    #pragma unroll
    for (int u=0;u<4;++u){
      const int kk = kb + 4*u;
      if (mrow){
        float4 h0 = ld4(hs + (size_t)gmA*Cc + kk);
        float4 mx = ld4(mrow + kk);
        float4 hp = make_float4(0.f,0.f,0.f,0.f);
        if ((gmA & (Tt-1)) != 0) hp = ld4(hs + (size_t)(gmA-1)*Cc + kk);
        pa[u].x = h0.x + (hp.x - h0.x)*mx.x;
        pa[u].y = h0.y + (hp.y - h0.y)*mx.y;
        pa[u].z = h0.z + (hp.z - h0.z)*mx.z;
        pa[u].w = h0.w + (hp.w - h0.w)*mx.w;
      } else {
        pa[u] = ld4(d.A + (size_t)gmA*K + kk);
      }
    }
    pwh[0] = *(const uint4*)(WH + (size_t)gnB*K + kb);
    pwh[1] = *(const uint4*)(WH + (size_t)gnB*K + kb + 8);
    pwl[0] = *(const uint4*)(WL + (size_t)gnB*K + kb);
    pwl[1] = *(const uint4*)(WL + (size_t)gnB*K + kb + 8);
  };

  const int wv = tid >> 6, lane = tid & 63;
  const int wm = (wv >> 1) << 6, wn = (wv & 1) << 6;
  const int fr = lane & 15;
  const int fk = (lane >> 4) << 3;

  f32x4 acc[4][4];
  const f32x4 z4 = {0.f,0.f,0.f,0.f};
  #pragma unroll
  for (int i=0;i<4;++i)
    #pragma unroll
    for (int j=0;j<4;++j) acc[i][j]=z4;

  const int nslab = K >> 5;
  load_slab(0);
  for (int kt=0; kt<nslab; ++kt){
    __syncthreads();
    {
      unsigned hw[8], lw[8];
      #pragma unroll
      for (int u=0;u<4;++u){
        const float xs[4] = {pa[u].x, pa[u].y, pa[u].z, pa[u].w};
        #pragma unroll
        for (int c=0;c<2;++c){
          unsigned u0 = __float_as_uint(xs[2*c]);
          unsigned u1 = __float_as_uint(xs[2*c+1]);
          float l0 = xs[2*c]   - __uint_as_float(u0 & 0xFFFF0000u);
          float l1 = xs[2*c+1] - __uint_as_float(u1 & 0xFFFF0000u);
          hw[u*2+c] = (u0>>16) | (u1 & 0xFFFF0000u);
          lw[u*2+c] = (__float_as_uint(l0)>>16) | (__float_as_uint(l1) & 0xFFFF0000u);
        }
      }
      uint4 t;
      t.x=hw[0];t.y=hw[1];t.z=hw[2];t.w=hw[3]; *(uint4*)&Ah[sr*LDBS+sk]   = t;
      t.x=hw[4];t.y=hw[5];t.z=hw[6];t.w=hw[7]; *(uint4*)&Ah[sr*LDBS+sk+8] = t;
      t.x=lw[0];t.y=lw[1];t.z=lw[2];t.w=lw[3]; *(uint4*)&Al[sr*LDBS+sk]   = t;
      t.x=lw[4];t.y=lw[5];t.z=lw[6];t.w=lw[7]; *(uint4*)&Al[sr*LDBS+sk+8] = t;
      *(uint4*)&Bh[sr*LDBS+sk]   = pwh[0];
      *(uint4*)&Bh[sr*LDBS+sk+8] = pwh[1];
      *(uint4*)&Bl[sr*LDBS+sk]   = pwl[0];
      *(uint4*)&Bl[sr*LDBS+sk+8] = pwl[1];
    }
    __syncthreads();
    if (kt+1 < nslab) load_slab(kt+1);

    short8 bh4[4], bl4[4];
    #pragma unroll
    for (int nt=0;nt<4;++nt){
      bh4[nt] = *(const short8*)&Bh[(wn + nt*16 + fr)*LDBS + fk];
      bl4[nt] = *(const short8*)&Bl[(wn + nt*16 + fr)*LDBS + fk];
    }
    #pragma unroll
    for (int mt=0;mt<4;++mt){
      const short8 ah = *(const short8*)&Ah[(wm + mt*16 + fr)*LDBS + fk];
      const short8 al = *(const short8*)&Al[(wm + mt*16 + fr)*LDBS + fk];
      #pragma unroll
      for (int nt=0;nt<4;++nt)
        acc[mt][nt] = __builtin_amdgcn_mfma_f32_16x16x32_bf16(ah, bh4[nt], acc[mt][nt], 0,0,0);
      #pragma unroll
      for (int nt=0;nt<4;++nt)
        acc[mt][nt] = __builtin_amdgcn_mfma_f32_16x16x32_bf16(ah, bl4[nt], acc[mt][nt], 0,0,0);
      #pragma unroll
      for (int nt=0;nt<4;++nt)
        acc[mt][nt] = __builtin_amdgcn_mfma_f32_16x16x32_bf16(al, bh4[nt], acc[mt][nt], 0,0,0);
    }
  }

  #pragma unroll
  for (int mt=0;mt<4;++mt){
    #pragma unroll
    for (int nt=0;nt<4;++nt){
      #pragma unroll
      for (int r=0;r<4;++r){
        const int row = wm + mt*16 + ((lane>>4)<<2) + r;
        const int col = wn + nt*16 + fr;
        d.out[(size_t)(m0+row)*d.N + n0 + col] = acc[mt][nt][r];
      }
    }
  }
}

// ---------------- per-head prep (in-place coefficient precompute) ----------------
__global__ __launch_bounds__(256) void head_prep(
    float* kbuf, float* awbuf, float* svwbuf, float* wbbuf, float* vbuf,
    const float* __restrict__ vfirst,
    const float* __restrict__ k_k, const float* __restrict__ k_a)
{
  const int gid = blockIdx.x*4 + (threadIdx.x>>6);
  const int e = threadIdx.x & 63;
  const int m = gid >> 4;
  const int h = gid & 15;
  const int c = h*Dd + e;
  const size_t idx = (size_t)m*Cc + c;
  const float kv0 = kbuf[idx];
  const float av  = awbuf[idx];
  const float sv  = svwbuf[idx];
  const float wv  = wbbuf[idx];
  const float v0  = vbuf[idx];
  const float vf  = vfirst[idx];
  const float kku = kv0 * k_k[c];
  const float ss  = wredsum(kku*kku);
  const float kkn = kku / fmaxf(sqrtf(ss), 1e-12f);
  const float ew  = expf(wv);
  kbuf[idx]  = kv0 * (1.f + (av - 1.f)*k_a[c]);
  awbuf[idx] = ew;
  svwbuf[idx]= -kkn * ew;
  wbbuf[idx] = kkn * av;
  vbuf[idx]  = v0 + sv*(vf - v0);
}

// ---------------- sequential scan v15: 2-chain interleave per wave ----------------
// 256 one-wave blocks. Block = (colquad q=blk>>4, head p=blk&15); the wave runs
// BOTH chains (b=0,h=p) and (b=1,h=p) interleaved. Rationale (v9..v14 ladder):
// per-step wall ~340cy = serial dep chain ~230cy (13-14 links, DPP-heavy) that a
// lone in-order wave can't fill — one step has only ~45 independent ops (~90cy).
// A second INDEPENDENT chain in the same wave supplies the missing filler: its
// instructions are textually interleaved into the first chain's stall slots
// (dsum16x4 = 4 independent DPP reductions interleaved). SMT (v12) proved
// cross-wave filling doesn't shorten a wave's own wall; this is in-wave.
// Step body per chain = v9 (deferred-output dual-dot, bit-identical math).
// Coefficients: global->VGPR (L2-resident), 4-deep static pipeline per chain.
struct Coef { float4 Lw, Ew, Bq, Kq, Rq; float Vv; };
__global__ __launch_bounds__(64) void scan_kernel(
    const float* __restrict__ lawb, const float* __restrict__ ewb,
    const float* __restrict__ bbb,  const float* __restrict__ kb,
    const float* __restrict__ rb,   const float* __restrict__ vb,
    float* __restrict__ outp)
{
  const int blk  = blockIdx.x;      // 0..255
  const int p    = blk & 15;        // head
  const int blkc = blk >> 4;        // 0..15: column quad
  const int lane = threadIdx.x;
  const int es = lane >> 4;         // column slot 0..3
  const int rd = lane & 15;         // row quad (rows 4rd..4rd+3)
  const int colb = blkc * 4;
  const int hb = p * Dd;
  const int la = 4*rd;              // dword offset of this lane's row quad

  // chain A: b=0; chain B: b=1
  float SA0=0.f, SA1=0.f, SA2=0.f, SA3=0.f;
  float SB0=0.f, SB1=0.f, SB2=0.f, SB3=0.f;
  float4 RpA = make_float4(0.f,0.f,0.f,0.f);
  float4 RpB = make_float4(0.f,0.f,0.f,0.f);

  const unsigned baseCA = hb + la;                          // b=0 float index
  const unsigned baseVA = hb + colb + es;
  const unsigned baseCB = (unsigned)(Tt*Cc) + hb + la;      // b=1
  const unsigned baseVB = (unsigned)(Tt*Cc) + hb + colb + es;
  float* ocolA = outp + hb + colb + es;
  float* ocolB = outp + (size_t)Tt*Cc + hb + colb + es;

  Coef CA[4], CB[4];
  auto ldgA = [&](int t, Coef& c){
    const unsigned tt = (t < Tt) ? (unsigned)t : (unsigned)(Tt-1);
    const unsigned oc = baseCA + tt*Cc;
    c.Lw = ld4(lawb + oc); c.Ew = ld4(ewb + oc); c.Bq = ld4(bbb + oc);
    c.Kq = ld4(kb + oc);   c.Rq = ld4(rb + oc);
    c.Vv = vb[baseVA + tt*Cc];
  };
  auto ldgB = [&](int t, Coef& c){
    const unsigned tt = (t < Tt) ? (unsigned)t : (unsigned)(Tt-1);
    const unsigned oc = baseCB + tt*Cc;
    c.Lw = ld4(lawb + oc); c.Ew = ld4(ewb + oc); c.Bq = ld4(bbb + oc);
    c.Kq = ld4(kb + oc);   c.Rq = ld4(rb + oc);
    c.Vv = vb[baseVB + tt*Cc];
  };

  #pragma unroll
  for (int i=0;i<4;++i){ ldgA(i, CA[i]); ldgB(i, CB[i]); }

  // one interleaved pair-step: advances BOTH chains by one timestep.
  auto pairstep = [&](int t, Coef& ca, Coef& cb){
    // partials (A then B, all independent until their own dsum chains)
    float tpA = fmaf(ca.Lw.y, SA1, ca.Lw.x*SA0);
    float tbA = fmaf(ca.Lw.w, SA3, ca.Lw.z*SA2);
    tpA += tbA;
    float opA = fmaf(RpA.y, SA1, RpA.x*SA0);
    float obA = fmaf(RpA.w, SA3, RpA.z*SA2);
    opA += obA;
    float tpB = fmaf(cb.Lw.y, SB1, cb.Lw.x*SB0);
    float tbB = fmaf(cb.Lw.w, SB3, cb.Lw.z*SB2);
    tpB += tbB;
    float opB = fmaf(RpB.y, SB1, RpB.x*SB0);
    float obB = fmaf(RpB.w, SB3, RpB.z*SB2);
    opB += obB;
    dsum16x4(tpA, opA, tpB, opB);     // 4 independent interleaved reductions
    if ((t > 0) && rd == 0){
      ocolA[(size_t)(t - 1)*Cc] = opA;
      ocolB[(size_t)(t - 1)*Cc] = opB;
    }
    SA0 = fmaf(ca.Ew.x, SA0, fmaf(ca.Bq.x, tpA, ca.Kq.x*ca.Vv));
    SA1 = fmaf(ca.Ew.y, SA1, fmaf(ca.Bq.y, tpA, ca.Kq.y*ca.Vv));
    SA2 = fmaf(ca.Ew.z, SA2, fmaf(ca.Bq.z, tpA, ca.Kq.z*ca.Vv));
    SA3 = fmaf(ca.Ew.w, SA3, fmaf(ca.Bq.w, tpA, ca.Kq.w*ca.Vv));
    SB0 = fmaf(cb.Ew.x, SB0, fmaf(cb.Bq.x, tpB, cb.Kq.x*cb.Vv));
    SB1 = fmaf(cb.Ew.y, SB1, fmaf(cb.Bq.y, tpB, cb.Kq.y*cb.Vv));
    SB2 = fmaf(cb.Ew.z, SB2, fmaf(cb.Bq.z, tpB, cb.Kq.z*cb.Vv));
    SB3 = fmaf(cb.Ew.w, SB3, fmaf(cb.Bq.w, tpB, cb.Kq.w*cb.Vv));
    RpA = ca.Rq;
    RpB = cb.Rq;
  };

  for (int g = 0; g < Tt; g += 4){
    #pragma unroll
    for (int i=0;i<4;++i){
      pairstep(g+i, CA[i], CB[i]);
      ldgA(g+4+i, CA[i]);        // refill 4 pair-steps ahead (~1000cy)
      ldgB(g+4+i, CB[i]);
    }
  }

  // flush: out(T-1) for both chains
  {
    float opA = fmaf(RpA.y, SA1, RpA.x*SA0);
    float obA = fmaf(RpA.w, SA3, RpA.z*SA2);
    opA += obA;
    float opB = fmaf(RpB.y, SB1, RpB.x*SB0);
    float obB = fmaf(RpB.w, SB3, RpB.z*SB2);
    opB += obB;
    dsum16x2(opA, opB);
    if (rd == 0){
      ocolA[(size_t)(Tt - 1)*Cc] = opA;
      ocolB[(size_t)(Tt - 1)*Cc] = opB;
    }
  }
}

// ---------------- GroupNorm + correction + g gating ----------------
__global__ __launch_bounds__(256) void epilogue_kernel(
    const float* __restrict__ att, const float* __restrict__ rbuf,
    const float* __restrict__ kbuf, const float* __restrict__ vbuf,
    const float* __restrict__ gbuf,
    const float* __restrict__ r_k, const float* __restrict__ gn_w,
    const float* __restrict__ gn_b, float* __restrict__ opre)
{
  const int gid = blockIdx.x*4 + (threadIdx.x>>6);
  const int e = threadIdx.x & 63;
  const int m = gid >> 4;
  const int h = gid & 15;
  const int c = h*Dd + e;
  const size_t idx = (size_t)m*Cc + c;
  const float x  = att[idx];
  const float mu = wredsum(x) * (1.f/Dd);
  const float xd = x - mu;
  const float var = wredsum(xd*xd) * (1.f/Dd);
  const float og = xd * (1.f/sqrtf(var + GN_EPS)) * gn_w[c] + gn_b[c];
  const float rv = rbuf[idx], kv = kbuf[idx], vv = vbuf[idx];
  const float cd = wredsum(rv*kv*r_k[c]);
  opre[idx] = (og + cd*vv) * gbuf[idx];
}

extern "C" void kernel_launch(void* const* d_in, const int* in_sizes, int n_in,
                              void* d_out, int out_size, void* d_ws, size_t ws_size,
                              hipStream_t stream)
{
  (void)in_sizes; (void)n_in; (void)out_size; (void)ws_size;
  const float* hs     = (const float*)d_in[0];
  const float* vfirst = (const float*)d_in[1];
  const float* xmix   = (const float*)d_in[2];
  const float* k_k    = (const float*)d_in[3];
  const float* k_a    = (const float*)d_in[4];
  const float* r_k    = (const float*)d_in[5];
  const float* W_r    = (const float*)d_in[6];
  const float* W_k    = (const float*)d_in[7];
  const float* W_v    = (const float*)d_in[8];
  const float* W_o    = (const float*)d_in[9];
  const float* w_A    = (const float*)d_in[10];
  const float* w_B    = (const float*)d_in[11];
  const float* w_b    = (const float*)d_in[12];
  const float* a_A    = (const float*)d_in[13];
  const float* a_B    = (const float*)d_in[14];
  const float* a_b    = (const float*)d_in[15];
  const float* v_A    = (const float*)d_in[16];
  const float* v_B    = (const float*)d_in[17];
  const float* v_b    = (const float*)d_in[18];
  const float* g_A    = (const float*)d_in[19];
  const float* g_B    = (const float*)d_in[20];
  const float* gn_w   = (const float*)d_in[21];
  const float* gn_b   = (const float*)d_in[22];
  float* out = (float*)d_out;
  float* ws  = (float*)d_ws;

  const size_t MC = (size_t)Mm * Cc;
  float* Br   = ws;            // r
  float* Bw   = ws + MC;       // w -> bb (head_prep) -> o_pre (epilogue)
  float* Bk   = ws + 2*MC;     // k0 -> kfin
  float* Bkk  = ws + 3*MC;     // sv -> law
  float* Bv   = ws + 4*MC;     // v0 -> v
  float* Ba   = ws + 5*MC;     // a -> ew
  float* Batt = ws + 6*MC;     // scan output
  float* Bg   = ws + 7*MC;     // g
  float* T1w  = ws + 8*MC;
  float* T1a  = T1w + (size_t)Mm*64;
  float* T1v  = T1a + (size_t)Mm*64;
  float* T1g  = T1v + (size_t)Mm*64;   // Mm*160 floats
  unsigned short* WP = (unsigned short*)(ws + 8*MC + (size_t)Mm*352);
  unsigned short* WrH = WP + 0*(size_t)NPL, *WrL = WP + 1*(size_t)NPL;
  unsigned short* WkH = WP + 2*(size_t)NPL, *WkL = WP + 3*(size_t)NPL;
  unsigned short* WvH = WP + 4*(size_t)NPL, *WvL = WP + 5*(size_t)NPL;
  unsigned short* WoH = WP + 6*(size_t)NPL, *WoL = WP + 7*(size_t)NPL;

  dim3 blk(256,1,1);

  // L0: weight split (W_r, W_k, W_v, W_o -> bf16 hi/lo planes)
  wsplit_kernel<<<dim3(NPL/(256*4),1,4), blk, 0, stream>>>(W_r, W_k, W_v, W_o, WP);

  // L1: big projections r, k0, v0 via split-bf16 MFMA
  GemmDesc dr{nullptr, W_r, Br, nullptr, Cc, Cc, 0, 0};
  GemmDesc dk{nullptr, W_k, Bk, nullptr, Cc, Cc, 2, 0};
  GemmDesc dv{nullptr, W_v, Bv, nullptr, Cc, Cc, 3, 0};
  gemm_mfma<<<dim3(Cc/TN, Mm/TM, 3), blk, 0, stream>>>(
      dr, dk, dv, WrH, WrL, WkH, WkL, WvH, WvL, xmix, hs);

  // L2: LoRA stage-1 (w: tanh; a: none; v: none; g: sigmoid)
  GemmDesc s1w{nullptr, w_A, T1w, nullptr, 64, Cc, 1, 1};
  GemmDesc s1a{nullptr, a_A, T1a, nullptr, 64, Cc, 4, 0};
  GemmDesc s1v{nullptr, v_A, T1v, nullptr, 64, Cc, 3, 0};
  GemmDesc s1g{nullptr, g_A, T1g, nullptr, 160, Cc, 5, 2};
  gemm_kernel<<<dim3(2,32,4), blk, 0, stream>>>(s1w,s1a,s1v,s1g, xmix, hs);

  // L3: LoRA stage-2
  GemmDesc s2w{T1w, w_B, Bw,  w_b,    Cc, 64,  -1, 3};
  GemmDesc s2a{T1a, a_B, Ba,  a_b,    Cc, 64,  -1, 2};
  GemmDesc s2v{T1v, v_B, Bkk, v_b,    Cc, 64,  -1, 2};
  GemmDesc s2g{T1g, g_B, Bg,  nullptr,Cc, 160, -1, 0};
  gemm_kernel<<<dim3(8,32,4), blk, 0, stream>>>(s2w,s2a,s2v,s2g, xmix, hs);

  // L4: per-head prep; in place: Bk k0->kfin, Ba a->ew, Bkk sv->law, Bw w->bb, Bv v0->v
  head_prep<<<dim3(Mm*Hh/4), blk, 0, stream>>>(Bk, Ba, Bkk, Bw, Bv,
                                               vfirst, k_k, k_a);

  // L5: sequential scan (v15: 2 chains per wave, in-wave latency filling)
  scan_kernel<<<dim3(256), dim3(64), 0, stream>>>(Bkk, Ba, Bw, Bk, Br, Bv, Batt);

  // L6: groupnorm + corr + g -> o_pre (reuse Bw; bb dead after scan)
  epilogue_kernel<<<dim3(Mm*Hh/4), blk, 0, stream>>>(Batt, Br, Bk, Bv, Bg,
                                                     r_k, gn_w, gn_b, Bw);

  // L7: output projection via split-bf16 MFMA
  GemmDesc doo{Bw, W_o, out, nullptr, Cc, Cc, -1, 0};
  gemm_mfma<<<dim3(Cc/TN, Mm/TM, 1), blk, 0, stream>>>(
      doo, doo, doo, WoH, WoL, WoH, WoL, WoH, WoL, xmix, hs);
}

// Round 10
// 697.674 us; speedup vs baseline: 1.0064x; 1.0064x over previous
//
#include <hip/hip_runtime.h>
#include <math.h>

#define Bb 2
#define Tt 1024
#define Cc 1024
#define Hh 16
#define Dd 64
#define Mm (Bb*Tt)
#define MCe ((size_t)Mm*Cc)
#define DECAY_SCALE (-0.6065306597126334f)
#define GN_EPS (64e-5f)

typedef __attribute__((ext_vector_type(8))) short short8;   // 8 bf16 (4 VGPRs)
typedef __attribute__((ext_vector_type(4))) float f32x4;    // MFMA acc

struct GemmDesc {
  const float* A;      // used when mixrow < 0 (row stride = K)
  const float* W;      // (N, K) row-major
  float* out;          // (M, N) row-major
  const float* bias;   // per-n bias or nullptr
  int N, K;
  int mixrow;          // >=0: A = token-shift mix of hidden_states with x_mix[mixrow]
  int ep;              // 0 none, 1 tanh, 2 sigmoid(x+bias?), 3 DECAY*sigmoid(x+bias)
};

// pre-split bf16 operands for the MFMA GEMM
struct MfmaDesc {
  const unsigned short *AH, *AL;   // A hi/lo planes (M x K bf16)
  const unsigned short *WH, *WL;   // W hi/lo planes (N x K bf16)
  float* out;                      // (M, N)
};

__device__ __forceinline__ float4 ld4(const float* p){ return *reinterpret_cast<const float4*>(p); }
__device__ __forceinline__ float sigmf(float x){ return 1.f/(1.f+expf(-x)); }

__device__ __forceinline__ float wredsum(float x){
  #pragma unroll
  for (int off=32; off>0; off>>=1) x += __shfl_xor(x, off);
  return x;
}

template<int CTRL>
__device__ __forceinline__ float dppadd(float x){
  return x + __int_as_float(__builtin_amdgcn_update_dpp(0, __float_as_int(x), CTRL, 0xF, 0xF, true));
}

// 16-lane sum (lanes 16k..16k+15), pure DPP (VALU speed, no LDS pipe).
__device__ __forceinline__ float dsum16(float x){
  x = dppadd<0xB1>(x);
  x = dppadd<0x4E>(x);
  x = dppadd<0x141>(x);
  x = dppadd<0x140>(x);
  return x;
}

// two independent 16-lane sums, explicitly interleaved so the second chain's
// DPP latency hides under the first chain's stalls (single-wave in-order issue).
__device__ __forceinline__ void dsum16x2(float& x, float& y){
  x = dppadd<0xB1>(x);  y = dppadd<0xB1>(y);
  x = dppadd<0x4E>(x);  y = dppadd<0x4E>(y);
  x = dppadd<0x141>(x); y = dppadd<0x141>(y);
  x = dppadd<0x140>(x); y = dppadd<0x140>(y);
}

// async global -> LDS DMA (16 B / 4 B per lane); dest = wave-uniform base + lane*size
__device__ __forceinline__ void gl2lds16(const float* g, float* l){
  __builtin_amdgcn_global_load_lds(
      (const __attribute__((address_space(1))) unsigned int*)g,
      (__attribute__((address_space(3))) unsigned int*)l, 16, 0, 0);
}
__device__ __forceinline__ void gl2lds4(const float* g, float* l){
  __builtin_amdgcn_global_load_lds(
      (const __attribute__((address_space(1))) unsigned int*)g,
      (__attribute__((address_space(3))) unsigned int*)l, 4, 0, 0);
}

// split one fp32 value pair into packed bf16 hi/lo words (exact same bit-math
// as the original in-loop split -> results bit-identical).
__device__ __forceinline__ void split2(const float a, const float b,
                                       unsigned& hw, unsigned& lw){
  unsigned u0 = __float_as_uint(a);
  unsigned u1 = __float_as_uint(b);
  float l0 = a - __uint_as_float(u0 & 0xFFFF0000u);
  float l1 = b - __uint_as_float(u1 & 0xFFFF0000u);
  hw = (u0>>16) | (u1 & 0xFFFF0000u);
  lw = (__float_as_uint(l0)>>16) | (__float_as_uint(l1) & 0xFFFF0000u);
}

// ---------------- vector-ALU GEMM (LoRA stages only) ----------------
#define BM 64
#define BN 128
#define BK 32

__global__ __launch_bounds__(256) void gemm_kernel(
    GemmDesc d0, GemmDesc d1, GemmDesc d2, GemmDesc d3,
    const float* __restrict__ xmix, const float* __restrict__ hs)
{
  GemmDesc d = (blockIdx.z==0)?d0:(blockIdx.z==1)?d1:(blockIdx.z==2)?d2:d3;
  const int n0 = blockIdx.x * BN;
  if (n0 >= d.N) return;            // block-uniform
  const int m0 = blockIdx.y * BM;
  const int tid = threadIdx.x;
  __shared__ float As[BK][BM+4];
  __shared__ float Bs[BK][BN+4];
  const int ty = tid >> 4, tx = tid & 15;

  float acc[4][8];
  #pragma unroll
  for (int i=0;i<4;++i)
    #pragma unroll
    for (int j=0;j<8;++j) acc[i][j]=0.f;

  const int K = d.K;
  const int nt = K / BK;
  const float* mrow = (d.mixrow >= 0) ? (xmix + (size_t)d.mixrow * Cc) : nullptr;
  float4 pa[2], pb[4];

  auto load_tile = [&](int kt){
    const int kbase = kt * BK;
    #pragma unroll
    for (int u=0;u<2;++u){
      const int li = tid + u*256;
      const int ar = li >> 3;
      const int kk = ((li & 7) << 2) + kbase;
      const int gm = m0 + ar;
      if (mrow){
        float4 h0 = ld4(hs + (size_t)gm*Cc + kk);
        float4 mx = ld4(mrow + kk);
        float4 hp = make_float4(0.f,0.f,0.f,0.f);
        if ((gm & (Tt-1)) != 0) hp = ld4(hs + (size_t)(gm-1)*Cc + kk);
        pa[u].x = h0.x + (hp.x - h0.x)*mx.x;
        pa[u].y = h0.y + (hp.y - h0.y)*mx.y;
        pa[u].z = h0.z + (hp.z - h0.z)*mx.z;
        pa[u].w = h0.w + (hp.w - h0.w)*mx.w;
      } else {
        pa[u] = ld4(d.A + (size_t)gm*K + kk);
      }
    }
    #pragma unroll
    for (int u=0;u<4;++u){
      const int li = tid + u*256;
      const int br = li >> 3;
      const int kk = ((li & 7) << 2) + kbase;
      const int gn = n0 + br;
      pb[u] = (gn < d.N) ? ld4(d.W + (size_t)gn*K + kk) : make_float4(0.f,0.f,0.f,0.f);
    }
  };

  load_tile(0);
  for (int kt=0; kt<nt; ++kt){
    __syncthreads();
    #pragma unroll
    for (int u=0;u<2;++u){
      const int li = tid + u*256;
      const int ar = li >> 3;
      const int kc = (li & 7) << 2;
      As[kc+0][ar] = pa[u].x; As[kc+1][ar] = pa[u].y;
      As[kc+2][ar] = pa[u].z; As[kc+3][ar] = pa[u].w;
    }
    #pragma unroll
    for (int u=0;u<4;++u){
      const int li = tid + u*256;
      const int br = li >> 3;
      const int kc = (li & 7) << 2;
      Bs[kc+0][br] = pb[u].x; Bs[kc+1][br] = pb[u].y;
      Bs[kc+2][br] = pb[u].z; Bs[kc+3][br] = pb[u].w;
    }
    __syncthreads();
    if (kt+1 < nt) load_tile(kt+1);
    #pragma unroll
    for (int kk=0;kk<BK;++kk){
      const float4 a0 = *(const float4*)&As[kk][ty<<2];
      const float4 b0 = *(const float4*)&Bs[kk][tx<<3];
      const float4 b1 = *(const float4*)&Bs[kk][(tx<<3)+4];
      const float av[4] = {a0.x,a0.y,a0.z,a0.w};
      const float bv[8] = {b0.x,b0.y,b0.z,b0.w,b1.x,b1.y,b1.z,b1.w};
      #pragma unroll
      for (int i=0;i<4;++i)
        #pragma unroll
        for (int j=0;j<8;++j)
          acc[i][j] = fmaf(av[i], bv[j], acc[i][j]);
    }
  }

  const int ep = d.ep;
  #pragma unroll
  for (int i=0;i<4;++i){
    const int gm = m0 + (ty<<2) + i;
    float* orow = d.out + (size_t)gm * d.N;
    #pragma unroll
    for (int j=0;j<8;++j){
      const int gn = n0 + (tx<<3) + j;
      if (gn < d.N){
        float x = acc[i][j];
        if (ep==1) x = tanhf(x);
        else if (ep==2){ if (d.bias) x += d.bias[gn]; x = sigmf(x); }
        else if (ep==3){ x += d.bias[gn]; x = DECAY_SCALE * sigmf(x); }
        orow[gn] = x;
      }
    }
  }
}

// ---------------- weight split pre-pass (fp32 -> bf16 hi/lo planes) ----------------
#define NPL (Cc*Cc)
__global__ __launch_bounds__(256) void wsplit_kernel(
    const float* __restrict__ s0, const float* __restrict__ s1,
    const float* __restrict__ s2, const float* __restrict__ s3,
    unsigned short* __restrict__ planes)
{
  const int z = blockIdx.z;
  const float* src = z==0?s0:z==1?s1:z==2?s2:s3;
  unsigned short* dh = planes + (size_t)z*2*NPL;
  unsigned short* dl = dh + NPL;
  const size_t i = ((size_t)blockIdx.x*256 + threadIdx.x)*4;
  float4 v = ld4(src + i);
  unsigned hw0, lw0, hw1, lw1;
  split2(v.x, v.y, hw0, lw0);
  split2(v.z, v.w, hw1, lw1);
  uint2 hv; hv.x = hw0; hv.y = hw1;
  uint2 lv; lv.x = lw0; lv.y = lw1;
  *(uint2*)(dh + i) = hv;
  *(uint2*)(dl + i) = lv;
}

// ---------------- activation split pre-pass (token-shift mix + bf16 hi/lo) --------
// z selects (plane buffer, mixrow): z=0 -> (p0, xr=0), z=1 -> (p1, xk=2), z=2 -> (p2, xv=3).
// Hoists the per-tile mix+split OUT of gemm_mfma's hot loop (it was recomputed
// redundantly by all 8 N-blocks). Bit-identical math (split2).
__global__ __launch_bounds__(256) void asplit_kernel(
    const float* __restrict__ hs, const float* __restrict__ xmix,
    unsigned short* __restrict__ p0, unsigned short* __restrict__ p1,
    unsigned short* __restrict__ p2)
{
  const int z = blockIdx.z;
  unsigned short* ph = z==0?p0:(z==1?p1:p2);
  const int mr = z==0?0:(z==1?2:3);
  const size_t o = ((size_t)blockIdx.x*256 + threadIdx.x)*4;
  const int gm = (int)(o >> 10);          // Cc = 1024
  const int kk = (int)(o & 1023);
  float4 h0 = ld4(hs + o);
  float4 mx = ld4(xmix + (size_t)mr*Cc + kk);
  float4 hp = make_float4(0.f,0.f,0.f,0.f);
  if ((gm & (Tt-1)) != 0) hp = ld4(hs + o - Cc);
  float x0 = h0.x + (hp.x - h0.x)*mx.x;
  float x1 = h0.y + (hp.y - h0.y)*mx.y;
  float x2 = h0.z + (hp.z - h0.z)*mx.z;
  float x3 = h0.w + (hp.w - h0.w)*mx.w;
  unsigned hw0, lw0, hw1, lw1;
  split2(x0, x1, hw0, lw0);
  split2(x2, x3, hw1, lw1);
  uint2 hv; hv.x = hw0; hv.y = hw1;
  uint2 lv; lv.x = lw0; lv.y = lw1;
  *(uint2*)(ph + o) = hv;
  *(uint2*)(ph + MCe + o) = lv;
}

// plain fp32 -> bf16 hi/lo split (for L7's input, produced by L6)
__global__ __launch_bounds__(256) void split1_kernel(
    const float* __restrict__ src, unsigned short* __restrict__ ph)
{
  const size_t o = ((size_t)blockIdx.x*256 + threadIdx.x)*4;
  float4 v = ld4(src + o);
  unsigned hw0, lw0, hw1, lw1;
  split2(v.x, v.y, hw0, lw0);
  split2(v.z, v.w, hw1, lw1);
  uint2 hv; hv.x = hw0; hv.y = hw1;
  uint2 lv; lv.x = lw0; lv.y = lw1;
  *(uint2*)(ph + o) = hv;
  *(uint2*)(ph + MCe + o) = lv;
}

// ---------------- split-bf16 MFMA GEMM (big projections) ----------------
// v2: consumes PRE-SPLIT bf16 hi/lo planes for BOTH operands. The per-tile
// fp32->bf16 split + token-shift mix that used to run in the hot loop (~60
// VALU/thread/kt, redundant across the 8 N-blocks) is gone — the loop is now
// loads + LDS writes + MFMA only.
#define TM 128
#define TN 128
#define LDBS 40   // bf16 row stride in LDS

__global__ __launch_bounds__(256) void gemm_mfma(MfmaDesc d0, MfmaDesc d1, MfmaDesc d2)
{
  const int z = blockIdx.z;
  MfmaDesc d = z==0?d0:(z==1?d1:d2);
  const int m0 = blockIdx.y * TM;
  const int n0 = blockIdx.x * TN;
  const int K  = Cc;
  const int tid = threadIdx.x;

  __shared__ __align__(16) unsigned short Ah[TM*LDBS], Al[TM*LDBS];
  __shared__ __align__(16) unsigned short Bh[TN*LDBS], Bl[TN*LDBS];

  const int sr = tid >> 1;
  const int sk = (tid & 1) << 4;
  const int gmA = m0 + sr;
  const int gnB = n0 + sr;

  uint4 pah[2], pal[2], pwh[2], pwl[2];
  auto load_slab = [&](int kt){
    const int kb = kt*32 + sk;
    pah[0] = *(const uint4*)(d.AH + (size_t)gmA*K + kb);
    pah[1] = *(const uint4*)(d.AH + (size_t)gmA*K + kb + 8);
    pal[0] = *(const uint4*)(d.AL + (size_t)gmA*K + kb);
    pal[1] = *(const uint4*)(d.AL + (size_t)gmA*K + kb + 8);
    pwh[0] = *(const uint4*)(d.WH + (size_t)gnB*K + kb);
    pwh[1] = *(const uint4*)(d.WH + (size_t)gnB*K + kb + 8);
    pwl[0] = *(const uint4*)(d.WL + (size_t)gnB*K + kb);
    pwl[1] = *(const uint4*)(d.WL + (size_t)gnB*K + kb + 8);
  };

  const int wv = tid >> 6, lane = tid & 63;
  const int wm = (wv >> 1) << 6, wn = (wv & 1) << 6;
  const int fr = lane & 15;
  const int fk = (lane >> 4) << 3;

  f32x4 acc[4][4];
  const f32x4 z4 = {0.f,0.f,0.f,0.f};
  #pragma unroll
  for (int i=0;i<4;++i)
    #pragma unroll
    for (int j=0;j<4;++j) acc[i][j]=z4;

  const int nslab = K >> 5;
  load_slab(0);
  for (int kt=0; kt<nslab; ++kt){
    __syncthreads();
    *(uint4*)&Ah[sr*LDBS+sk]   = pah[0];
    *(uint4*)&Ah[sr*LDBS+sk+8] = pah[1];
    *(uint4*)&Al[sr*LDBS+sk]   = pal[0];
    *(uint4*)&Al[sr*LDBS+sk+8] = pal[1];
    *(uint4*)&Bh[sr*LDBS+sk]   = pwh[0];
    *(uint4*)&Bh[sr*LDBS+sk+8] = pwh[1];
    *(uint4*)&Bl[sr*LDBS+sk]   = pwl[0];
    *(uint4*)&Bl[sr*LDBS+sk+8] = pwl[1];
    __syncthreads();
    if (kt+1 < nslab) load_slab(kt+1);

    short8 bh4[4], bl4[4];
    #pragma unroll
    for (int nt=0;nt<4;++nt){
      bh4[nt] = *(const short8*)&Bh[(wn + nt*16 + fr)*LDBS + fk];
      bl4[nt] = *(const short8*)&Bl[(wn + nt*16 + fr)*LDBS + fk];
    }
    #pragma unroll
    for (int mt=0;mt<4;++mt){
      const short8 ah = *(const short8*)&Ah[(wm + mt*16 + fr)*LDBS + fk];
      const short8 al = *(const short8*)&Al[(wm + mt*16 + fr)*LDBS + fk];
      #pragma unroll
      for (int nt=0;nt<4;++nt)
        acc[mt][nt] = __builtin_amdgcn_mfma_f32_16x16x32_bf16(ah, bh4[nt], acc[mt][nt], 0,0,0);
      #pragma unroll
      for (int nt=0;nt<4;++nt)
        acc[mt][nt] = __builtin_amdgcn_mfma_f32_16x16x32_bf16(ah, bl4[nt], acc[mt][nt], 0,0,0);
      #pragma unroll
      for (int nt=0;nt<4;++nt)
        acc[mt][nt] = __builtin_amdgcn_mfma_f32_16x16x32_bf16(al, bh4[nt], acc[mt][nt], 0,0,0);
    }
  }

  #pragma unroll
  for (int mt=0;mt<4;++mt){
    #pragma unroll
    for (int nt=0;nt<4;++nt){
      #pragma unroll
      for (int r=0;r<4;++r){
        const int row = wm + mt*16 + ((lane>>4)<<2) + r;
        const int col = wn + nt*16 + fr;
        d.out[(size_t)(m0+row)*Cc + n0 + col] = acc[mt][nt][r];
      }
    }
  }
}

// ---------------- per-head prep (in-place coefficient precompute) ----------------
__global__ __launch_bounds__(256) void head_prep(
    float* kbuf, float* awbuf, float* svwbuf, float* wbbuf, float* vbuf,
    const float* __restrict__ vfirst,
    const float* __restrict__ k_k, const float* __restrict__ k_a)
{
  const int gid = blockIdx.x*4 + (threadIdx.x>>6);
  const int e = threadIdx.x & 63;
  const int m = gid >> 4;
  const int h = gid & 15;
  const int c = h*Dd + e;
  const size_t idx = (size_t)m*Cc + c;
  const float kv0 = kbuf[idx];
  const float av  = awbuf[idx];
  const float sv  = svwbuf[idx];
  const float wv  = wbbuf[idx];
  const float v0  = vbuf[idx];
  const float vf  = vfirst[idx];
  const float kku = kv0 * k_k[c];
  const float ss  = wredsum(kku*kku);
  const float kkn = kku / fmaxf(sqrtf(ss), 1e-12f);
  const float ew  = expf(wv);
  kbuf[idx]  = kv0 * (1.f + (av - 1.f)*k_a[c]);
  awbuf[idx] = ew;
  svwbuf[idx]= -kkn * ew;
  wbbuf[idx] = kkn * av;
  vbuf[idx]  = v0 + sv*(vf - v0);
}

// ---------------- sequential scan v13: 4-deep register pipeline + counted vmcnt ----
// (best scan variant: 143.5us. v14 global-reg and v15 2-chain-interleave both
// regressed — the ~344cy/step floor tracks instruction count at ~6-7cy/instr
// for a lone wave; scheduling tricks don't reach it.)
#define NB (Tt/16)
struct Coef { float4 Lw, Ew, Bq, Kq, Rq; float Vv; };
__global__ __launch_bounds__(64) void scan_kernel(
    const float* __restrict__ lawb, const float* __restrict__ ewb,
    const float* __restrict__ bbb,  const float* __restrict__ kb,
    const float* __restrict__ rb,   const float* __restrict__ vb,
    float* __restrict__ outp)
{
  const int blk  = blockIdx.x;
  const int bh   = blk & 31;        // chain id; 16 blocks %32-congruent -> same XCD
  const int blkc = blk >> 5;        // 0..15: column quad
  const int b = bh >> 4, h = bh & 15;
  const int lane = threadIdx.x;
  const int es = lane >> 4;         // column slot 0..3
  const int rd = lane & 15;         // row quad (rows 4rd..4rd+3)
  const int colb = blkc * 4;
  const int hb = h * Dd;
  const int la = 4*rd;              // dword offset of this lane's row quad

  // per buffer: law[1024] ew[1024] bb[1024] k[1024] r[1024] v[64]
  __shared__ __align__(16) float LB[2][5*1024 + 64];

  float S0=0.f, S1=0.f, S2=0.f, S3=0.f;
  float4 Rp = make_float4(0.f,0.f,0.f,0.f);   // r of previous step (r_{g-1})
  const size_t mbase = (size_t)b*Tt;
  float* ocol = outp + mbase*Cc + hb + colb + es;   // column base for rd==0 stores

  const int qrow = lane >> 4;           // staging: row within 4-row slab
  const int qcol = (lane & 15) * 4;     // staging: dword col

  auto stage = [&](int bt){
    const size_t g0 = (mbase + (size_t)bt*16)*Cc + hb;
    float* dst = &LB[bt&1][0];
    const float* srcs[5] = {lawb, ewb, bbb, kb, rb};
    #pragma unroll
    for (int a=0;a<5;++a){
      const float* s = srcs[a] + g0 + (size_t)qrow*Cc + qcol;
      #pragma unroll
      for (int i=0;i<4;++i)
        gl2lds16(s + (size_t)(4*i)*Cc, dst + a*1024 + i*256);
    }
    gl2lds4(vb + g0 + (size_t)(lane>>2)*Cc + colb + (lane&3), dst + 5120);
  };

  stage(0);
  __builtin_amdgcn_s_waitcnt(0x0F70);   // vmcnt(0): batch 0's DMA complete

  for (int bt = 0; bt < NB; ++bt){
    if (bt+1 < NB) stage(bt+1);           // in flight under this batch's compute
    const float* cb2 = &LB[bt&1][0];

    auto ldq = [&](int t, Coef& c){
      c.Lw = *(const float4*)&cb2[         t*64 + la];
      c.Ew = *(const float4*)&cb2[1024 + t*64 + la];
      c.Bq = *(const float4*)&cb2[2048 + t*64 + la];
      c.Kq = *(const float4*)&cb2[3072 + t*64 + la];
      c.Rq = *(const float4*)&cb2[4096 + t*64 + la];
      c.Vv = cb2[5120 + t*4 + es];
    };

    Coef cA, cB, cC, cD;
    ldq(0, cA); ldq(1, cB); ldq(2, cC); ldq(3, cD);

    auto stepf = [&](int t, Coef& c){
      const float4 Lw = c.Lw, Ew = c.Ew, Bq = c.Bq, Kq = c.Kq, rr = c.Rq;
      const float vv = c.Vv;
      // both dots read S_old: ta for THIS step's update, op for PREVIOUS step's output
      float tp = fmaf(Lw.y, S1, Lw.x*S0);
      float tb = fmaf(Lw.w, S3, Lw.z*S2);
      tp += tb;
      float op = fmaf(Rp.y, S1, Rp.x*S0);
      float ob = fmaf(Rp.w, S3, Rp.z*S2);
      op += ob;
      dsum16x2(tp, op);                       // interleaved: op hides under tp's chain
      // store out(g-1); only batch 0 / t==0 has no predecessor
      const bool gv = (bt > 0) | (t > 0);
      if (gv && rd == 0)
        ocol[(size_t)(bt*16 + t - 1)*Cc] = op;
      S0 = fmaf(Ew.x, S0, fmaf(Bq.x, tp, Kq.x*vv));
      S1 = fmaf(Ew.y, S1, fmaf(Bq.y, tp, Kq.y*vv));
      S2 = fmaf(Ew.z, S2, fmaf(Bq.z, tp, Kq.z*vv));
      S3 = fmaf(Ew.w, S3, fmaf(Bq.w, tp, Kq.w*vv));
      Rp = rr;                                // r_g becomes r_{g-1} for next step
      if (t+4 < 16) ldq(t+4, c);              // refill same buffer, 4 steps ahead
    };

    #pragma unroll
    for (int t = 0; t < 16; ++t){
      const int s = t & 3;
      if      (s == 0) stepf(t, cA);
      else if (s == 1) stepf(t, cB);
      else if (s == 2) stepf(t, cC);
      else             stepf(t, cD);
    }

    // counted wait: stage(bt+1)'s 22 DMA ops are the OLDEST outstanding vm ops;
    // <=16 output stores were issued after them. vmcnt(16) => all DMA landed.
    if (bt+1 < NB) __builtin_amdgcn_s_waitcnt(0x4F70);   // vmcnt(16)
  }

  // flush: out(T-1) = r_{T-1} . S(T-1)
  {
    float op = fmaf(Rp.y, S1, Rp.x*S0);
    float ob = fmaf(Rp.w, S3, Rp.z*S2);
    op = dsum16(op + ob);
    if (rd == 0)
      ocol[(size_t)(Tt - 1)*Cc] = op;
  }
}

// ---------------- GroupNorm + correction + g gating ----------------
__global__ __launch_bounds__(256) void epilogue_kernel(
    const float* __restrict__ att, const float* __restrict__ rbuf,
    const float* __restrict__ kbuf, const float* __restrict__ vbuf,
    const float* __restrict__ gbuf,
    const float* __restrict__ r_k, const float* __restrict__ gn_w,
    const float* __restrict__ gn_b, float* __restrict__ opre)
{
  const int gid = blockIdx.x*4 + (threadIdx.x>>6);
  const int e = threadIdx.x & 63;
  const int m = gid >> 4;
  const int h = gid & 15;
  const int c = h*Dd + e;
  const size_t idx = (size_t)m*Cc + c;
  const float x  = att[idx];
  const float mu = wredsum(x) * (1.f/Dd);
  const float xd = x - mu;
  const float var = wredsum(xd*xd) * (1.f/Dd);
  const float og = xd * (1.f/sqrtf(var + GN_EPS)) * gn_w[c] + gn_b[c];
  const float rv = rbuf[idx], kv = kbuf[idx], vv = vbuf[idx];
  const float cd = wredsum(rv*kv*r_k[c]);
  opre[idx] = (og + cd*vv) * gbuf[idx];
}

extern "C" void kernel_launch(void* const* d_in, const int* in_sizes, int n_in,
                              void* d_out, int out_size, void* d_ws, size_t ws_size,
                              hipStream_t stream)
{
  (void)in_sizes; (void)n_in; (void)out_size; (void)ws_size;
  const float* hs     = (const float*)d_in[0];
  const float* vfirst = (const float*)d_in[1];
  const float* xmix   = (const float*)d_in[2];
  const float* k_k    = (const float*)d_in[3];
  const float* k_a    = (const float*)d_in[4];
  const float* r_k    = (const float*)d_in[5];
  const float* W_r    = (const float*)d_in[6];
  const float* W_k    = (const float*)d_in[7];
  const float* W_v    = (const float*)d_in[8];
  const float* W_o    = (const float*)d_in[9];
  const float* w_A    = (const float*)d_in[10];
  const float* w_B    = (const float*)d_in[11];
  const float* w_b    = (const float*)d_in[12];
  const float* a_A    = (const float*)d_in[13];
  const float* a_B    = (const float*)d_in[14];
  const float* a_b    = (const float*)d_in[15];
  const float* v_A    = (const float*)d_in[16];
  const float* v_B    = (const float*)d_in[17];
  const float* v_b    = (const float*)d_in[18];
  const float* g_A    = (const float*)d_in[19];
  const float* g_B    = (const float*)d_in[20];
  const float* gn_w   = (const float*)d_in[21];
  const float* gn_b   = (const float*)d_in[22];
  float* out = (float*)d_out;
  float* ws  = (float*)d_ws;

  const size_t MC = MCe;
  float* Br   = ws;            // r
  float* Bw   = ws + MC;       // [A-planes r] -> w/bb (L3/L4) -> o_pre (epilogue)
  float* Bk   = ws + 2*MC;     // k0 -> kfin
  float* Bkk  = ws + 3*MC;     // [A-planes k] -> sv -> law
  float* Bv   = ws + 4*MC;     // v0 -> v
  float* Ba   = ws + 5*MC;     // [A-planes v] -> a -> ew
  float* Batt = ws + 6*MC;     // scan output -> [A-planes o_pre for L7]
  float* Bg   = ws + 7*MC;     // g
  float* T1w  = ws + 8*MC;
  float* T1a  = T1w + (size_t)Mm*64;
  float* T1v  = T1a + (size_t)Mm*64;
  float* T1g  = T1v + (size_t)Mm*64;   // Mm*160 floats
  unsigned short* WP = (unsigned short*)(ws + 8*MC + (size_t)Mm*352);
  unsigned short* WrH = WP + 0*(size_t)NPL, *WrL = WP + 1*(size_t)NPL;
  unsigned short* WkH = WP + 2*(size_t)NPL, *WkL = WP + 3*(size_t)NPL;
  unsigned short* WvH = WP + 4*(size_t)NPL, *WvL = WP + 5*(size_t)NPL;
  unsigned short* WoH = WP + 6*(size_t)NPL, *WoL = WP + 7*(size_t)NPL;
  // A-plane pairs live in fp32 buffers that are dead during L1 (overwritten by L3):
  unsigned short* ArP = (unsigned short*)Bw;    // hi = ArP[0..MC), lo = ArP[MC..2MC)
  unsigned short* AkP = (unsigned short*)Bkk;
  unsigned short* AvP = (unsigned short*)Ba;
  unsigned short* AoP = (unsigned short*)Batt;  // L7 input planes (Batt dead after L6)

  dim3 blk(256,1,1);

  // L0: weight split (W_r, W_k, W_v, W_o -> bf16 hi/lo planes)
  wsplit_kernel<<<dim3(NPL/(256*4),1,4), blk, 0, stream>>>(W_r, W_k, W_v, W_o, WP);

  // L0b: activation split (token-shift mix + bf16 hi/lo) for r/k/v inputs
  asplit_kernel<<<dim3(Mm*Cc/(256*4),1,3), blk, 0, stream>>>(hs, xmix, ArP, AkP, AvP);

  // L1: big projections r, k0, v0 via split-bf16 MFMA (pre-split operands)
  MfmaDesc dr{ArP, ArP+MC, WrH, WrL, Br};
  MfmaDesc dk{AkP, AkP+MC, WkH, WkL, Bk};
  MfmaDesc dv{AvP, AvP+MC, WvH, WvL, Bv};
  gemm_mfma<<<dim3(Cc/TN, Mm/TM, 3), blk, 0, stream>>>(dr, dk, dv);

  // L2: LoRA stage-1 (w: tanh; a: none; v: none; g: sigmoid)
  GemmDesc s1w{nullptr, w_A, T1w, nullptr, 64, Cc, 1, 1};
  GemmDesc s1a{nullptr, a_A, T1a, nullptr, 64, Cc, 4, 0};
  GemmDesc s1v{nullptr, v_A, T1v, nullptr, 64, Cc, 3, 0};
  GemmDesc s1g{nullptr, g_A, T1g, nullptr, 160, Cc, 5, 2};
  gemm_kernel<<<dim3(2,32,4), blk, 0, stream>>>(s1w,s1a,s1v,s1g, xmix, hs);

  // L3: LoRA stage-2 (overwrites the L1 A-plane buffers — planes dead by now)
  GemmDesc s2w{T1w, w_B, Bw,  w_b,    Cc, 64,  -1, 3};
  GemmDesc s2a{T1a, a_B, Ba,  a_b,    Cc, 64,  -1, 2};
  GemmDesc s2v{T1v, v_B, Bkk, v_b,    Cc, 64,  -1, 2};
  GemmDesc s2g{T1g, g_B, Bg,  nullptr,Cc, 160, -1, 0};
  gemm_kernel<<<dim3(8,32,4), blk, 0, stream>>>(s2w,s2a,s2v,s2g, xmix, hs);

  // L4: per-head prep; in place: Bk k0->kfin, Ba a->ew, Bkk sv->law, Bw w->bb, Bv v0->v
  head_prep<<<dim3(Mm*Hh/4), blk, 0, stream>>>(Bk, Ba, Bkk, Bw, Bv,
                                               vfirst, k_k, k_a);

  // L5: sequential scan (v13: 4-deep reg pipeline, counted vmcnt, no barriers)
  scan_kernel<<<dim3(512), dim3(64), 0, stream>>>(Bkk, Ba, Bw, Bk, Br, Bv, Batt);

  // L6: groupnorm + corr + g -> o_pre (reuse Bw; bb dead after scan)
  epilogue_kernel<<<dim3(Mm*Hh/4), blk, 0, stream>>>(Batt, Br, Bk, Bv, Bg,
                                                     r_k, gn_w, gn_b, Bw);

  // L6b: split o_pre into bf16 planes (Batt dead after L6)
  split1_kernel<<<dim3(Mm*Cc/(256*4)), blk, 0, stream>>>(Bw, AoP);

  // L7: output projection via split-bf16 MFMA
  MfmaDesc doo{AoP, AoP+MC, WoH, WoL, out};
  gemm_mfma<<<dim3(Cc/TN, Mm/TM, 1), blk, 0, stream>>>(doo, doo, doo);
}

// Round 11
// 589.479 us; speedup vs baseline: 1.1912x; 1.1835x over previous
//
#include <hip/hip_runtime.h>
#include <math.h>

#define Bb 2
#define Tt 1024
#define Cc 1024
#define Hh 16
#define Dd 64
#define Mm (Bb*Tt)
#define DECAY_SCALE (-0.6065306597126334f)
#define GN_EPS (64e-5f)

typedef __attribute__((ext_vector_type(8))) short short8;   // 8 bf16 (4 VGPRs)
typedef __attribute__((ext_vector_type(4))) float f32x4;    // MFMA acc

struct GemmDesc {
  const float* A;      // used when mixrow < 0 (row stride = K)
  const float* W;      // (N, K) row-major
  float* out;          // (M, N) row-major
  const float* bias;   // per-n bias or nullptr
  int N, K;
  int mixrow;          // >=0: A = token-shift mix of hidden_states with x_mix[mixrow]
  int ep;              // 0 none, 1 tanh, 2 sigmoid(x+bias?), 3 DECAY*sigmoid(x+bias)
};

__device__ __forceinline__ float4 ld4(const float* p){ return *reinterpret_cast<const float4*>(p); }
__device__ __forceinline__ float sigmf(float x){ return 1.f/(1.f+expf(-x)); }

__device__ __forceinline__ float wredsum(float x){
  #pragma unroll
  for (int off=32; off>0; off>>=1) x += __shfl_xor(x, off);
  return x;
}

template<int CTRL>
__device__ __forceinline__ float dppadd(float x){
  return x + __int_as_float(__builtin_amdgcn_update_dpp(0, __float_as_int(x), CTRL, 0xF, 0xF, true));
}

// 16-lane sum (lanes 16k..16k+15), pure DPP (VALU speed, no LDS pipe).
__device__ __forceinline__ float dsum16(float x){
  x = dppadd<0xB1>(x);
  x = dppadd<0x4E>(x);
  x = dppadd<0x141>(x);
  x = dppadd<0x140>(x);
  return x;
}

// two independent 16-lane sums, explicitly interleaved so the second chain's
// DPP latency hides under the first chain's stalls (single-wave in-order issue).
__device__ __forceinline__ void dsum16x2(float& x, float& y){
  x = dppadd<0xB1>(x);  y = dppadd<0xB1>(y);
  x = dppadd<0x4E>(x);  y = dppadd<0x4E>(y);
  x = dppadd<0x141>(x); y = dppadd<0x141>(y);
  x = dppadd<0x140>(x); y = dppadd<0x140>(y);
}

// async global -> LDS DMA (16 B / 4 B per lane); dest = wave-uniform base + lane*size
__device__ __forceinline__ void gl2lds16(const float* g, float* l){
  __builtin_amdgcn_global_load_lds(
      (const __attribute__((address_space(1))) unsigned int*)g,
      (__attribute__((address_space(3))) unsigned int*)l, 16, 0, 0);
}
__device__ __forceinline__ void gl2lds4(const float* g, float* l){
  __builtin_amdgcn_global_load_lds(
      (const __attribute__((address_space(1))) unsigned int*)g,
      (__attribute__((address_space(3))) unsigned int*)l, 4, 0, 0);
}

// ---------------- vector-ALU GEMM (LoRA stages only) ----------------
#define BM 64
#define BN 128
#define BK 32

__global__ __launch_bounds__(256) void gemm_kernel(
    GemmDesc d0, GemmDesc d1, GemmDesc d2, GemmDesc d3,
    const float* __restrict__ xmix, const float* __restrict__ hs)
{
  GemmDesc d = (blockIdx.z==0)?d0:(blockIdx.z==1)?d1:(blockIdx.z==2)?d2:d3;
  const int n0 = blockIdx.x * BN;
  if (n0 >= d.N) return;            // block-uniform
  const int m0 = blockIdx.y * BM;
  const int tid = threadIdx.x;
  __shared__ float As[BK][BM+4];
  __shared__ float Bs[BK][BN+4];
  const int ty = tid >> 4, tx = tid & 15;

  float acc[4][8];
  #pragma unroll
  for (int i=0;i<4;++i)
    #pragma unroll
    for (int j=0;j<8;++j) acc[i][j]=0.f;

  const int K = d.K;
  const int nt = K / BK;
  const float* mrow = (d.mixrow >= 0) ? (xmix + (size_t)d.mixrow * Cc) : nullptr;
  float4 pa[2], pb[4];

  auto load_tile = [&](int kt){
    const int kbase = kt * BK;
    #pragma unroll
    for (int u=0;u<2;++u){
      const int li = tid + u*256;
      const int ar = li >> 3;
      const int kk = ((li & 7) << 2) + kbase;
      const int gm = m0 + ar;
      if (mrow){
        float4 h0 = ld4(hs + (size_t)gm*Cc + kk);
        float4 mx = ld4(mrow + kk);
        float4 hp = make_float4(0.f,0.f,0.f,0.f);
        if ((gm & (Tt-1)) != 0) hp = ld4(hs + (size_t)(gm-1)*Cc + kk);
        pa[u].x = h0.x + (hp.x - h0.x)*mx.x;
        pa[u].y = h0.y + (hp.y - h0.y)*mx.y;
        pa[u].z = h0.z + (hp.z - h0.z)*mx.z;
        pa[u].w = h0.w + (hp.w - h0.w)*mx.w;
      } else {
        pa[u] = ld4(d.A + (size_t)gm*K + kk);
      }
    }
    #pragma unroll
    for (int u=0;u<4;++u){
      const int li = tid + u*256;
      const int br = li >> 3;
      const int kk = ((li & 7) << 2) + kbase;
      const int gn = n0 + br;
      pb[u] = (gn < d.N) ? ld4(d.W + (size_t)gn*K + kk) : make_float4(0.f,0.f,0.f,0.f);
    }
  };

  load_tile(0);
  for (int kt=0; kt<nt; ++kt){
    __syncthreads();
    #pragma unroll
    for (int u=0;u<2;++u){
      const int li = tid + u*256;
      const int ar = li >> 3;
      const int kc = (li & 7) << 2;
      As[kc+0][ar] = pa[u].x; As[kc+1][ar] = pa[u].y;
      As[kc+2][ar] = pa[u].z; As[kc+3][ar] = pa[u].w;
    }
    #pragma unroll
    for (int u=0;u<4;++u){
      const int li = tid + u*256;
      const int br = li >> 3;
      const int kc = (li & 7) << 2;
      Bs[kc+0][br] = pb[u].x; Bs[kc+1][br] = pb[u].y;
      Bs[kc+2][br] = pb[u].z; Bs[kc+3][br] = pb[u].w;
    }
    __syncthreads();
    if (kt+1 < nt) load_tile(kt+1);
    #pragma unroll
    for (int kk=0;kk<BK;++kk){
      const float4 a0 = *(const float4*)&As[kk][ty<<2];
      const float4 b0 = *(const float4*)&Bs[kk][tx<<3];
      const float4 b1 = *(const float4*)&Bs[kk][(tx<<3)+4];
      const float av[4] = {a0.x,a0.y,a0.z,a0.w};
      const float bv[8] = {b0.x,b0.y,b0.z,b0.w,b1.x,b1.y,b1.z,b1.w};
      #pragma unroll
      for (int i=0;i<4;++i)
        #pragma unroll
        for (int j=0;j<8;++j)
          acc[i][j] = fmaf(av[i], bv[j], acc[i][j]);
    }
  }

  const int ep = d.ep;
  #pragma unroll
  for (int i=0;i<4;++i){
    const int gm = m0 + (ty<<2) + i;
    float* orow = d.out + (size_t)gm * d.N;
    #pragma unroll
    for (int j=0;j<8;++j){
      const int gn = n0 + (tx<<3) + j;
      if (gn < d.N){
        float x = acc[i][j];
        if (ep==1) x = tanhf(x);
        else if (ep==2){ if (d.bias) x += d.bias[gn]; x = sigmf(x); }
        else if (ep==3){ x += d.bias[gn]; x = DECAY_SCALE * sigmf(x); }
        orow[gn] = x;
      }
    }
  }
}

// ---------------- weight split pre-pass (fp32 -> bf16 hi/lo planes) ----------------
#define NPL (Cc*Cc)
__global__ __launch_bounds__(256) void wsplit_kernel(
    const float* __restrict__ s0, const float* __restrict__ s1,
    const float* __restrict__ s2, const float* __restrict__ s3,
    unsigned short* __restrict__ planes)
{
  const int z = blockIdx.z;
  const float* src = z==0?s0:z==1?s1:z==2?s2:s3;
  unsigned short* dh = planes + (size_t)z*2*NPL;
  unsigned short* dl = dh + NPL;
  const size_t i = ((size_t)blockIdx.x*256 + threadIdx.x)*4;
  float4 v = ld4(src + i);
  const float xs[4] = {v.x, v.y, v.z, v.w};
  unsigned hw[2], lw[2];
  #pragma unroll
  for (int c=0;c<2;++c){
    unsigned u0 = __float_as_uint(xs[2*c]);
    unsigned u1 = __float_as_uint(xs[2*c+1]);
    float l0 = xs[2*c]   - __uint_as_float(u0 & 0xFFFF0000u);
    float l1 = xs[2*c+1] - __uint_as_float(u1 & 0xFFFF0000u);
    hw[c] = (u0>>16) | (u1 & 0xFFFF0000u);
    lw[c] = (__float_as_uint(l0)>>16) | (__float_as_uint(l1) & 0xFFFF0000u);
  }
  uint2 hv; hv.x = hw[0]; hv.y = hw[1];
  uint2 lv; lv.x = lw[0]; lv.y = lw[1];
  *(uint2*)(dh + i) = hv;
  *(uint2*)(dl + i) = lv;
}

// ---------------- fp32 premix pre-pass (token-shift mix only, NO split) -----------
// z -> (buffer, mixrow): z=0 -> (p0, xr=0), z=1 -> (p1, xk=2), z=2 -> (p2, xv=3).
// Hoists the lerp out of gemm_mfma's loop WITHOUT changing its memory character:
// A stays ONE fp32 stream of 8MB/slice (vs h0+mx+hp = 3 streams in-loop).
// Identical fma forms -> bit-identical results. (Round-10 lesson: pre-SPLIT
// bf16 planes tripled the streaming set and thrashed L2; fp32 premix doesn't.)
__global__ __launch_bounds__(256) void premix_kernel(
    const float* __restrict__ hs, const float* __restrict__ xmix,
    float* __restrict__ p0, float* __restrict__ p1, float* __restrict__ p2)
{
  const int z = blockIdx.z;
  float* ph = z==0?p0:(z==1?p1:p2);
  const int mr = z==0?0:(z==1?2:3);
  const size_t o = ((size_t)blockIdx.x*256 + threadIdx.x)*4;
  const int gm = (int)(o >> 10);          // Cc = 1024
  const int kk = (int)(o & 1023);
  float4 h0 = ld4(hs + o);
  float4 mx = ld4(xmix + (size_t)mr*Cc + kk);
  float4 hp = make_float4(0.f,0.f,0.f,0.f);
  if ((gm & (Tt-1)) != 0) hp = ld4(hs + o - Cc);
  float4 r;
  r.x = h0.x + (hp.x - h0.x)*mx.x;
  r.y = h0.y + (hp.y - h0.y)*mx.y;
  r.z = h0.z + (hp.z - h0.z)*mx.z;
  r.w = h0.w + (hp.w - h0.w)*mx.w;
  *(float4*)(ph + o) = r;
}

// ---------------- split-bf16 MFMA GEMM (big projections) ----------------
// A is a plain fp32 buffer (premixed for L1; epilogue output for L7); the
// fp32 -> bf16 hi/lo split stays IN-LOOP (round-10 lesson: global pre-split
// planes trade VALU for L2-thrashing streams and lose).
#define TM 128
#define TN 128
#define LDBS 40   // bf16 row stride in LDS

__global__ __launch_bounds__(256) void gemm_mfma(
    GemmDesc d0, GemmDesc d1, GemmDesc d2,
    const unsigned short* __restrict__ WH0, const unsigned short* __restrict__ WL0,
    const unsigned short* __restrict__ WH1, const unsigned short* __restrict__ WL1,
    const unsigned short* __restrict__ WH2, const unsigned short* __restrict__ WL2)
{
  const int z = blockIdx.z;
  GemmDesc d = z==0?d0:(z==1?d1:d2);
  const unsigned short* WH = z==0?WH0:(z==1?WH1:WH2);
  const unsigned short* WL = z==0?WL0:(z==1?WL1:WL2);
  const int m0 = blockIdx.y * TM;
  const int n0 = blockIdx.x * TN;
  const int K  = d.K;
  const int tid = threadIdx.x;

  __shared__ __align__(16) unsigned short Ah[TM*LDBS], Al[TM*LDBS];
  __shared__ __align__(16) unsigned short Bh[TN*LDBS], Bl[TN*LDBS];

  const int sr = tid >> 1;
  const int sk = (tid & 1) << 4;
  const int gmA = m0 + sr;
  const int gnB = n0 + sr;

  float4 pa[4];
  uint4 pwh[2], pwl[2];
  auto load_slab = [&](int kt){
    const int kb = kt*32 + sk;
    #pragma unroll
    for (int u=0;u<4;++u)
      pa[u] = ld4(d.A + (size_t)gmA*K + kb + 4*u);
    pwh[0] = *(const uint4*)(WH + (size_t)gnB*K + kb);
    pwh[1] = *(const uint4*)(WH + (size_t)gnB*K + kb + 8);
    pwl[0] = *(const uint4*)(WL + (size_t)gnB*K + kb);
    pwl[1] = *(const uint4*)(WL + (size_t)gnB*K + kb + 8);
  };

  const int wv = tid >> 6, lane = tid & 63;
  const int wm = (wv >> 1) << 6, wn = (wv & 1) << 6;
  const int fr = lane & 15;
  const int fk = (lane >> 4) << 3;

  f32x4 acc[4][4];
  const f32x4 z4 = {0.f,0.f,0.f,0.f};
  #pragma unroll
  for (int i=0;i<4;++i)
    #pragma unroll
    for (int j=0;j<4;++j) acc[i][j]=z4;

  const int nslab = K >> 5;
  load_slab(0);
  for (int kt=0; kt<nslab; ++kt){
    __syncthreads();
    {
      unsigned hw[8], lw[8];
      #pragma unroll
      for (int u=0;u<4;++u){
        const float xs[4] = {pa[u].x, pa[u].y, pa[u].z, pa[u].w};
        #pragma unroll
        for (int c=0;c<2;++c){
          unsigned u0 = __float_as_uint(xs[2*c]);
          unsigned u1 = __float_as_uint(xs[2*c+1]);
          float l0 = xs[2*c]   - __uint_as_float(u0 & 0xFFFF0000u);
          float l1 = xs[2*c+1] - __uint_as_float(u1 & 0xFFFF0000u);
          hw[u*2+c] = (u0>>16) | (u1 & 0xFFFF0000u);
          lw[u*2+c] = (__float_as_uint(l0)>>16) | (__float_as_uint(l1) & 0xFFFF0000u);
        }
      }
      uint4 t;
      t.x=hw[0];t.y=hw[1];t.z=hw[2];t.w=hw[3]; *(uint4*)&Ah[sr*LDBS+sk]   = t;
      t.x=hw[4];t.y=hw[5];t.z=hw[6];t.w=hw[7]; *(uint4*)&Ah[sr*LDBS+sk+8] = t;
      t.x=lw[0];t.y=lw[1];t.z=lw[2];t.w=lw[3]; *(uint4*)&Al[sr*LDBS+sk]   = t;
      t.x=lw[4];t.y=lw[5];t.z=lw[6];t.w=lw[7]; *(uint4*)&Al[sr*LDBS+sk+8] = t;
      *(uint4*)&Bh[sr*LDBS+sk]   = pwh[0];
      *(uint4*)&Bh[sr*LDBS+sk+8] = pwh[1];
      *(uint4*)&Bl[sr*LDBS+sk]   = pwl[0];
      *(uint4*)&Bl[sr*LDBS+sk+8] = pwl[1];
    }
    __syncthreads();
    if (kt+1 < nslab) load_slab(kt+1);

    short8 bh4[4], bl4[4];
    #pragma unroll
    for (int nt=0;nt<4;++nt){
      bh4[nt] = *(const short8*)&Bh[(wn + nt*16 + fr)*LDBS + fk];
      bl4[nt] = *(const short8*)&Bl[(wn + nt*16 + fr)*LDBS + fk];
    }
    #pragma unroll
    for (int mt=0;mt<4;++mt){
      const short8 ah = *(const short8*)&Ah[(wm + mt*16 + fr)*LDBS + fk];
      const short8 al = *(const short8*)&Al[(wm + mt*16 + fr)*LDBS + fk];
      #pragma unroll
      for (int nt=0;nt<4;++nt)
        acc[mt][nt] = __builtin_amdgcn_mfma_f32_16x16x32_bf16(ah, bh4[nt], acc[mt][nt], 0,0,0);
      #pragma unroll
      for (int nt=0;nt<4;++nt)
        acc[mt][nt] = __builtin_amdgcn_mfma_f32_16x16x32_bf16(ah, bl4[nt], acc[mt][nt], 0,0,0);
      #pragma unroll
      for (int nt=0;nt<4;++nt)
        acc[mt][nt] = __builtin_amdgcn_mfma_f32_16x16x32_bf16(al, bh4[nt], acc[mt][nt], 0,0,0);
    }
  }

  #pragma unroll
  for (int mt=0;mt<4;++mt){
    #pragma unroll
    for (int nt=0;nt<4;++nt){
      #pragma unroll
      for (int r=0;r<4;++r){
        const int row = wm + mt*16 + ((lane>>4)<<2) + r;
        const int col = wn + nt*16 + fr;
        d.out[(size_t)(m0+row)*d.N + n0 + col] = acc[mt][nt][r];
      }
    }
  }
}

// ---------------- per-head prep (in-place coefficient precompute) ----------------
__global__ __launch_bounds__(256) void head_prep(
    float* kbuf, float* awbuf, float* svwbuf, float* wbbuf, float* vbuf,
    const float* __restrict__ vfirst,
    const float* __restrict__ k_k, const float* __restrict__ k_a)
{
  const int gid = blockIdx.x*4 + (threadIdx.x>>6);
  const int e = threadIdx.x & 63;
  const int m = gid >> 4;
  const int h = gid & 15;
  const int c = h*Dd + e;
  const size_t idx = (size_t)m*Cc + c;
  const float kv0 = kbuf[idx];
  const float av  = awbuf[idx];
  const float sv  = svwbuf[idx];
  const float wv  = wbbuf[idx];
  const float v0  = vbuf[idx];
  const float vf  = vfirst[idx];
  const float kku = kv0 * k_k[c];
  const float ss  = wredsum(kku*kku);
  const float kkn = kku / fmaxf(sqrtf(ss), 1e-12f);
  const float ew  = expf(wv);
  kbuf[idx]  = kv0 * (1.f + (av - 1.f)*k_a[c]);
  awbuf[idx] = ew;
  svwbuf[idx]= -kkn * ew;
  wbbuf[idx] = kkn * av;
  vbuf[idx]  = v0 + sv*(vf - v0);
}

// ---------------- sequential scan v13: 4-deep register pipeline + counted vmcnt ----
#define NB (Tt/16)
struct Coef { float4 Lw, Ew, Bq, Kq, Rq; float Vv; };
__global__ __launch_bounds__(64) void scan_kernel(
    const float* __restrict__ lawb, const float* __restrict__ ewb,
    const float* __restrict__ bbb,  const float* __restrict__ kb,
    const float* __restrict__ rb,   const float* __restrict__ vb,
    float* __restrict__ outp)
{
  const int blk  = blockIdx.x;
  const int bh   = blk & 31;        // chain id; 16 blocks %32-congruent -> same XCD
  const int blkc = blk >> 5;        // 0..15: column quad
  const int b = bh >> 4, h = bh & 15;
  const int lane = threadIdx.x;
  const int es = lane >> 4;         // column slot 0..3
  const int rd = lane & 15;         // row quad (rows 4rd..4rd+3)
  const int colb = blkc * 4;
  const int hb = h * Dd;
  const int la = 4*rd;              // dword offset of this lane's row quad

  // per buffer: law[1024] ew[1024] bb[1024] k[1024] r[1024] v[64]
  __shared__ __align__(16) float LB[2][5*1024 + 64];

  float S0=0.f, S1=0.f, S2=0.f, S3=0.f;
  float4 Rp = make_float4(0.f,0.f,0.f,0.f);   // r of previous step (r_{g-1})
  const size_t mbase = (size_t)b*Tt;
  float* ocol = outp + mbase*Cc + hb + colb + es;   // column base for rd==0 stores

  const int qrow = lane >> 4;           // staging: row within 4-row slab
  const int qcol = (lane & 15) * 4;     // staging: dword col

  auto stage = [&](int bt){
    const size_t g0 = (mbase + (size_t)bt*16)*Cc + hb;
    float* dst = &LB[bt&1][0];
    const float* srcs[5] = {lawb, ewb, bbb, kb, rb};
    #pragma unroll
    for (int a=0;a<5;++a){
      const float* s = srcs[a] + g0 + (size_t)qrow*Cc + qcol;
      #pragma unroll
      for (int i=0;i<4;++i)
        gl2lds16(s + (size_t)(4*i)*Cc, dst + a*1024 + i*256);
    }
    gl2lds4(vb + g0 + (size_t)(lane>>2)*Cc + colb + (lane&3), dst + 5120);
  };

  stage(0);
  __builtin_amdgcn_s_waitcnt(0x0F70);   // vmcnt(0): batch 0's DMA complete

  for (int bt = 0; bt < NB; ++bt){
    if (bt+1 < NB) stage(bt+1);           // in flight under this batch's compute
    const float* cb2 = &LB[bt&1][0];

    auto ldq = [&](int t, Coef& c){
      c.Lw = *(const float4*)&cb2[         t*64 + la];
      c.Ew = *(const float4*)&cb2[1024 + t*64 + la];
      c.Bq = *(const float4*)&cb2[2048 + t*64 + la];
      c.Kq = *(const float4*)&cb2[3072 + t*64 + la];
      c.Rq = *(const float4*)&cb2[4096 + t*64 + la];
      c.Vv = cb2[5120 + t*4 + es];
    };

    Coef cA, cB, cC, cD;
    ldq(0, cA); ldq(1, cB); ldq(2, cC); ldq(3, cD);

    auto stepf = [&](int t, Coef& c){
      const float4 Lw = c.Lw, Ew = c.Ew, Bq = c.Bq, Kq = c.Kq, rr = c.Rq;
      const float vv = c.Vv;
      // both dots read S_old: ta for THIS step's update, op for PREVIOUS step's output
      float tp = fmaf(Lw.y, S1, Lw.x*S0);
      float tb = fmaf(Lw.w, S3, Lw.z*S2);
      tp += tb;
      float op = fmaf(Rp.y, S1, Rp.x*S0);
      float ob = fmaf(Rp.w, S3, Rp.z*S2);
      op += ob;
      dsum16x2(tp, op);                       // interleaved: op hides under tp's chain
      // store out(g-1); only batch 0 / t==0 has no predecessor
      const bool gv = (bt > 0) | (t > 0);
      if (gv && rd == 0)
        ocol[(size_t)(bt*16 + t - 1)*Cc] = op;
      S0 = fmaf(Ew.x, S0, fmaf(Bq.x, tp, Kq.x*vv));
      S1 = fmaf(Ew.y, S1, fmaf(Bq.y, tp, Kq.y*vv));
      S2 = fmaf(Ew.z, S2, fmaf(Bq.z, tp, Kq.z*vv));
      S3 = fmaf(Ew.w, S3, fmaf(Bq.w, tp, Kq.w*vv));
      Rp = rr;                                // r_g becomes r_{g-1} for next step
      if (t+4 < 16) ldq(t+4, c);              // refill same buffer, 4 steps ahead
    };

    #pragma unroll
    for (int t = 0; t < 16; ++t){
      const int s = t & 3;
      if      (s == 0) stepf(t, cA);
      else if (s == 1) stepf(t, cB);
      else if (s == 2) stepf(t, cC);
      else             stepf(t, cD);
    }

    // counted wait: stage(bt+1)'s 22 DMA ops are the OLDEST outstanding vm ops;
    // <=16 output stores were issued after them. vmcnt(16) => all DMA landed.
    if (bt+1 < NB) __builtin_amdgcn_s_waitcnt(0x4F70);   // vmcnt(16)
  }

  // flush: out(T-1) = r_{T-1} . S(T-1)
  {
    float op = fmaf(Rp.y, S1, Rp.x*S0);
    float ob = fmaf(Rp.w, S3, Rp.z*S2);
    op = dsum16(op + ob);
    if (rd == 0)
      ocol[(size_t)(Tt - 1)*Cc] = op;
  }
}

// ---------------- GroupNorm + correction + g gating ----------------
__global__ __launch_bounds__(256) void epilogue_kernel(
    const float* __restrict__ att, const float* __restrict__ rbuf,
    const float* __restrict__ kbuf, const float* __restrict__ vbuf,
    const float* __restrict__ gbuf,
    const float* __restrict__ r_k, const float* __restrict__ gn_w,
    const float* __restrict__ gn_b, float* __restrict__ opre)
{
  const int gid = blockIdx.x*4 + (threadIdx.x>>6);
  const int e = threadIdx.x & 63;
  const int m = gid >> 4;
  const int h = gid & 15;
  const int c = h*Dd + e;
  const size_t idx = (size_t)m*Cc + c;
  const float x  = att[idx];
  const float mu = wredsum(x) * (1.f/Dd);
  const float xd = x - mu;
  const float var = wredsum(xd*xd) * (1.f/Dd);
  const float og = xd * (1.f/sqrtf(var + GN_EPS)) * gn_w[c] + gn_b[c];
  const float rv = rbuf[idx], kv = kbuf[idx], vv = vbuf[idx];
  const float cd = wredsum(rv*kv*r_k[c]);
  opre[idx] = (og + cd*vv) * gbuf[idx];
}

extern "C" void kernel_launch(void* const* d_in, const int* in_sizes, int n_in,
                              void* d_out, int out_size, void* d_ws, size_t ws_size,
                              hipStream_t stream)
{
  (void)in_sizes; (void)n_in; (void)out_size; (void)ws_size;
  const float* hs     = (const float*)d_in[0];
  const float* vfirst = (const float*)d_in[1];
  const float* xmix   = (const float*)d_in[2];
  const float* k_k    = (const float*)d_in[3];
  const float* k_a    = (const float*)d_in[4];
  const float* r_k    = (const float*)d_in[5];
  const float* W_r    = (const float*)d_in[6];
  const float* W_k    = (const float*)d_in[7];
  const float* W_v    = (const float*)d_in[8];
  const float* W_o    = (const float*)d_in[9];
  const float* w_A    = (const float*)d_in[10];
  const float* w_B    = (const float*)d_in[11];
  const float* w_b    = (const float*)d_in[12];
  const float* a_A    = (const float*)d_in[13];
  const float* a_B    = (const float*)d_in[14];
  const float* a_b    = (const float*)d_in[15];
  const float* v_A    = (const float*)d_in[16];
  const float* v_B    = (const float*)d_in[17];
  const float* v_b    = (const float*)d_in[18];
  const float* g_A    = (const float*)d_in[19];
  const float* g_B    = (const float*)d_in[20];
  const float* gn_w   = (const float*)d_in[21];
  const float* gn_b   = (const float*)d_in[22];
  float* out = (float*)d_out;
  float* ws  = (float*)d_ws;

  const size_t MC = (size_t)Mm * Cc;
  float* Br   = ws;            // r
  float* Bw   = ws + MC;       // [premix xr] -> w/bb (L3/L4) -> o_pre (epilogue)
  float* Bk   = ws + 2*MC;     // k0 -> kfin
  float* Bkk  = ws + 3*MC;     // [premix xk] -> sv -> law
  float* Bv   = ws + 4*MC;     // v0 -> v
  float* Ba   = ws + 5*MC;     // [premix xv] -> a -> ew
  float* Batt = ws + 6*MC;     // scan output
  float* Bg   = ws + 7*MC;     // g
  float* T1w  = ws + 8*MC;
  float* T1a  = T1w + (size_t)Mm*64;
  float* T1v  = T1a + (size_t)Mm*64;
  float* T1g  = T1v + (size_t)Mm*64;   // Mm*160 floats
  unsigned short* WP = (unsigned short*)(ws + 8*MC + (size_t)Mm*352);
  unsigned short* WrH = WP + 0*(size_t)NPL, *WrL = WP + 1*(size_t)NPL;
  unsigned short* WkH = WP + 2*(size_t)NPL, *WkL = WP + 3*(size_t)NPL;
  unsigned short* WvH = WP + 4*(size_t)NPL, *WvL = WP + 5*(size_t)NPL;
  unsigned short* WoH = WP + 6*(size_t)NPL, *WoL = WP + 7*(size_t)NPL;

  dim3 blk(256,1,1);

  // L0: weight split (W_r, W_k, W_v, W_o -> bf16 hi/lo planes)
  wsplit_kernel<<<dim3(NPL/(256*4),1,4), blk, 0, stream>>>(W_r, W_k, W_v, W_o, WP);

  // L0b: fp32 premix of token-shift inputs (xr -> Bw, xk -> Bkk, xv -> Ba;
  // these buffers are dead until L3 overwrites them)
  premix_kernel<<<dim3(Mm*Cc/(256*4),1,3), blk, 0, stream>>>(hs, xmix, Bw, Bkk, Ba);

  // L1: big projections r, k0, v0 via split-bf16 MFMA (premixed fp32 A)
  GemmDesc dr{Bw,  W_r, Br, nullptr, Cc, Cc, -1, 0};
  GemmDesc dk{Bkk, W_k, Bk, nullptr, Cc, Cc, -1, 0};
  GemmDesc dv{Ba,  W_v, Bv, nullptr, Cc, Cc, -1, 0};
  gemm_mfma<<<dim3(Cc/TN, Mm/TM, 3), blk, 0, stream>>>(
      dr, dk, dv, WrH, WrL, WkH, WkL, WvH, WvL);

  // L2: LoRA stage-1 (w: tanh; a: none; v: none; g: sigmoid)
  GemmDesc s1w{nullptr, w_A, T1w, nullptr, 64, Cc, 1, 1};
  GemmDesc s1a{nullptr, a_A, T1a, nullptr, 64, Cc, 4, 0};
  GemmDesc s1v{nullptr, v_A, T1v, nullptr, 64, Cc, 3, 0};
  GemmDesc s1g{nullptr, g_A, T1g, nullptr, 160, Cc, 5, 2};
  gemm_kernel<<<dim3(2,32,4), blk, 0, stream>>>(s1w,s1a,s1v,s1g, xmix, hs);

  // L3: LoRA stage-2 (overwrites the premix buffers — dead by now)
  GemmDesc s2w{T1w, w_B, Bw,  w_b,    Cc, 64,  -1, 3};
  GemmDesc s2a{T1a, a_B, Ba,  a_b,    Cc, 64,  -1, 2};
  GemmDesc s2v{T1v, v_B, Bkk, v_b,    Cc, 64,  -1, 2};
  GemmDesc s2g{T1g, g_B, Bg,  nullptr,Cc, 160, -1, 0};
  gemm_kernel<<<dim3(8,32,4), blk, 0, stream>>>(s2w,s2a,s2v,s2g, xmix, hs);

  // L4: per-head prep; in place: Bk k0->kfin, Ba a->ew, Bkk sv->law, Bw w->bb, Bv v0->v
  head_prep<<<dim3(Mm*Hh/4), blk, 0, stream>>>(Bk, Ba, Bkk, Bw, Bv,
                                               vfirst, k_k, k_a);

  // L5: sequential scan (v13: 4-deep reg pipeline, counted vmcnt, no barriers)
  scan_kernel<<<dim3(512), dim3(64), 0, stream>>>(Bkk, Ba, Bw, Bk, Br, Bv, Batt);

  // L6: groupnorm + corr + g -> o_pre (reuse Bw; bb dead after scan)
  epilogue_kernel<<<dim3(Mm*Hh/4), blk, 0, stream>>>(Batt, Br, Bk, Bv, Bg,
                                                     r_k, gn_w, gn_b, Bw);

  // L7: output projection via split-bf16 MFMA
  GemmDesc doo{Bw, W_o, out, nullptr, Cc, Cc, -1, 0};
  gemm_mfma<<<dim3(Cc/TN, Mm/TM, 1), blk, 0, stream>>>(
      doo, doo, doo, WoH, WoL, WoH, WoL, WoH, WoL);
}